// Round 1
// baseline (593.586 us; speedup 1.0000x reference)
//
#include <hip/hip_runtime.h>

// SpikingNeuralNetwork: B=32, S=4096, D=512, H=256, OUT=128
// out = broadcast_B( (1/S) * (Σ_s spikes[s,:]) @ W_h ), spikes from LIF scan over
// currents = x.mean(0) @ W_in.
//
// Kernel A (fused_mean_proj): fused batch-mean + input projection, HBM-bound
//   (reads x once, 268 MB). 512 blocks x 256 thr, TS=8 s-rows/block.
// Kernel B (snn_scan_out): sequential LIF scan, thread=h (256 independent
//   chains), spike COUNT only (spikes are 0/1 and output is a mean over s),
//   then 256x128 matvec epilogue + batch broadcast.

#define S_LEN 4096
#define D_DIM 512
#define H_DIM 256
#define O_DIM 128
#define B_SZ  32
#define TS    8     // s-rows per block in kernel A
#define UNR   16    // scan prefetch depth

__global__ __launch_bounds__(256)
void fused_mean_proj(const float4* __restrict__ x4,
                     const float*  __restrict__ iw,
                     float*        __restrict__ cur) {
    __shared__ float4 xm4[TS * D_DIM / 4];     // 8 rows x 512 f32 = 16 KB
    const int t   = threadIdx.x;
    const int s0  = blockIdx.x * TS;
    const int SD4 = S_LEN * D_DIM / 4;         // float4 elems per batch image
    const size_t base = (size_t)s0 * (D_DIM / 4);

    // Stage 1: sum x[b, s0:s0+TS, :] over b into registers (coalesced float4).
    float4 acc[4];
    #pragma unroll
    for (int k = 0; k < 4; ++k) acc[k] = make_float4(0.f, 0.f, 0.f, 0.f);

    for (int b = 0; b < B_SZ; ++b) {
        const float4* pb = x4 + (size_t)b * SD4 + base;
        #pragma unroll
        for (int k = 0; k < 4; ++k) {
            float4 v = pb[t + k * 256];
            acc[k].x += v.x; acc[k].y += v.y; acc[k].z += v.z; acc[k].w += v.w;
        }
    }
    const float inv = 1.0f / (float)B_SZ;
    #pragma unroll
    for (int k = 0; k < 4; ++k) {
        float4 a = acc[k];
        a.x *= inv; a.y *= inv; a.z *= inv; a.w *= inv;
        xm4[t + k * 256] = a;                  // LDS layout == tile layout
    }
    __syncthreads();

    // Stage 2: currents[s0+ss][h] = Σ_d xm[ss][d] * W_in[d][h]; thread = h.
    const int h = t;
    float acc2[TS];
    #pragma unroll
    for (int ss = 0; ss < TS; ++ss) acc2[ss] = 0.f;

    for (int d4 = 0; d4 < D_DIM / 4; ++d4) {
        const int d = d4 * 4;
        float w0 = iw[(d + 0) * H_DIM + h];    // coalesced across h; L2-resident
        float w1 = iw[(d + 1) * H_DIM + h];
        float w2 = iw[(d + 2) * H_DIM + h];
        float w3 = iw[(d + 3) * H_DIM + h];
        #pragma unroll
        for (int ss = 0; ss < TS; ++ss) {
            float4 xv = xm4[ss * (D_DIM / 4) + d4];   // broadcast read (same addr all lanes)
            acc2[ss] += xv.x * w0 + xv.y * w1 + xv.z * w2 + xv.w * w3;
        }
    }
    #pragma unroll
    for (int ss = 0; ss < TS; ++ss) {
        cur[(size_t)(s0 + ss) * H_DIM + h] = acc2[ss];
    }
}

__global__ __launch_bounds__(256)
void snn_scan_out(const float* __restrict__ cur,
                  const float* __restrict__ hw,
                  float*       __restrict__ out) {
    const int h = threadIdx.x;                 // one LIF chain per thread
    float mem = 0.f, refr = 0.f, cnt = 0.f;
    const float* p = cur + h;                  // column h; coalesced across lanes

    float buf[UNR];
    #pragma unroll
    for (int j = 0; j < UNR; ++j) buf[j] = p[j * H_DIM];

    for (int s0 = 0; s0 < S_LEN; s0 += UNR) {
        // Prefetch next group (chain-independent addresses) before processing.
        float nxt[UNR];
        if (s0 + UNR < S_LEN) {
            #pragma unroll
            for (int j = 0; j < UNR; ++j) nxt[j] = p[(size_t)(s0 + UNR + j) * H_DIM];
        } else {
            #pragma unroll
            for (int j = 0; j < UNR; ++j) nxt[j] = 0.f;
        }
        #pragma unroll
        for (int j = 0; j < UNR; ++j) {
            float ic = buf[j];
            // active = refr<=0; during refractory mem is exactly 0, so
            // spike => refr was 0 => refr_new = spike ? 2 : max(refr-1,0).
            float m  = 0.95f * mem + ((refr <= 0.f) ? ic : 0.f);
            bool  sp = (m >= 1.0f);
            cnt += sp ? 1.0f : 0.0f;
            mem  = sp ? 0.0f : m;
            refr = sp ? 2.0f : fmaxf(refr - 1.0f, 0.0f);
        }
        #pragma unroll
        for (int j = 0; j < UNR; ++j) buf[j] = nxt[j];
    }

    // Epilogue: out_mean[o] = Σ_h cnt[h] * W_h[h][o] / S, broadcast over batch.
    __shared__ float cnt_lds[H_DIM];
    cnt_lds[h] = cnt;
    __syncthreads();
    if (h < O_DIM) {
        float a = 0.f;
        for (int k = 0; k < H_DIM; ++k) a += cnt_lds[k] * hw[k * O_DIM + h];
        a *= (1.0f / (float)S_LEN);
        #pragma unroll
        for (int b = 0; b < B_SZ; ++b) out[b * O_DIM + h] = a;
    }
}

extern "C" void kernel_launch(void* const* d_in, const int* in_sizes, int n_in,
                              void* d_out, int out_size, void* d_ws, size_t ws_size,
                              hipStream_t stream) {
    const float4* x4 = (const float4*)d_in[0];       // [32,4096,512] f32
    const float*  iw = (const float*) d_in[1];       // [512,256] f32
    const float*  hw = (const float*) d_in[2];       // [256,128] f32
    float* out = (float*)d_out;                      // [32,128] f32
    float* cur = (float*)d_ws;                       // currents [4096,256] f32 = 4 MB

    hipLaunchKernelGGL(fused_mean_proj, dim3(S_LEN / TS), dim3(256), 0, stream,
                       x4, iw, cur);
    hipLaunchKernelGGL(snn_scan_out, dim3(1), dim3(256), 0, stream,
                       cur, hw, out);
}

// Round 2
// 549.682 us; speedup vs baseline: 1.0799x; 1.0799x over previous
//
#include <hip/hip_runtime.h>
#include <stdint.h>

// SpikingNeuralNetwork: B=32, S=4096, D=512, H=256, OUT=128
// out = broadcast_B( (1/S) * (Σ_s spikes[s,:]) @ W_h ), spikes from LIF scan over
// currents = x.mean(0) @ W_in.
//
// Kernel A (fused_mean_proj): fused batch-mean + input projection (reads x once,
//   268 MB). 512 blocks x 256 thr, TS=8 s-rows/block. b-loop unrolled x2 for
//   8 coalesced float4 loads in flight per wave.
// Kernel B (snn_scan_out): sequential LIF scan on ONE block (256 independent
//   h-chains). currents streamed via __builtin_amdgcn_global_load_lds into a
//   double-buffered LDS (2 x 32KB); one __syncthreads per chunk, placed so its
//   vmcnt(0) drain is a full chunk-scan after issue (latency hidden).
//   Refractory tracked as next-active step index sa (1 int cmp vs scalar s).

#define S_LEN 4096
#define D_DIM 512
#define H_DIM 256
#define O_DIM 128
#define B_SZ  32
#define TS    8                   // s-rows per block in kernel A
#define CH    32                  // scan chunk length (steps)
#define NCH   (S_LEN / CH)        // 128 chunks

typedef const __attribute__((address_space(1))) void  glob_void;
typedef       __attribute__((address_space(3))) void  lds_void;

__global__ __launch_bounds__(256)
void fused_mean_proj(const float4* __restrict__ x4,
                     const float*  __restrict__ iw,
                     float*        __restrict__ cur) {
    __shared__ float4 xm4[TS * D_DIM / 4];     // 8 rows x 512 f32 = 16 KB
    const int t   = threadIdx.x;
    const int s0  = blockIdx.x * TS;
    const int SD4 = S_LEN * D_DIM / 4;
    const size_t base = (size_t)s0 * (D_DIM / 4);

    // Stage 1: sum x[b, s0:s0+TS, :] over b (order-preserving, 8 loads in flight).
    float4 acc[4];
    #pragma unroll
    for (int k = 0; k < 4; ++k) acc[k] = make_float4(0.f, 0.f, 0.f, 0.f);

    for (int b = 0; b < B_SZ; b += 2) {
        const float4* p0 = x4 + (size_t)b * SD4 + base;
        const float4* p1 = p0 + SD4;
        float4 v0[4], v1[4];
        #pragma unroll
        for (int k = 0; k < 4; ++k) v0[k] = p0[t + k * 256];
        #pragma unroll
        for (int k = 0; k < 4; ++k) v1[k] = p1[t + k * 256];
        #pragma unroll
        for (int k = 0; k < 4; ++k) {
            acc[k].x += v0[k].x; acc[k].y += v0[k].y; acc[k].z += v0[k].z; acc[k].w += v0[k].w;
            acc[k].x += v1[k].x; acc[k].y += v1[k].y; acc[k].z += v1[k].z; acc[k].w += v1[k].w;
        }
    }
    const float inv = 1.0f / (float)B_SZ;
    #pragma unroll
    for (int k = 0; k < 4; ++k) {
        float4 a = acc[k];
        a.x *= inv; a.y *= inv; a.z *= inv; a.w *= inv;
        xm4[t + k * 256] = a;
    }
    __syncthreads();

    // Stage 2: currents[s0+ss][h] = Σ_d xm[ss][d] * W_in[d][h]; thread = h.
    const int h = t;
    float acc2[TS];
    #pragma unroll
    for (int ss = 0; ss < TS; ++ss) acc2[ss] = 0.f;

    for (int d4 = 0; d4 < D_DIM / 4; ++d4) {
        const int d = d4 * 4;
        float w0 = iw[(d + 0) * H_DIM + h];
        float w1 = iw[(d + 1) * H_DIM + h];
        float w2 = iw[(d + 2) * H_DIM + h];
        float w3 = iw[(d + 3) * H_DIM + h];
        #pragma unroll
        for (int ss = 0; ss < TS; ++ss) {
            float4 xv = xm4[ss * (D_DIM / 4) + d4];   // same-addr broadcast: free
            acc2[ss] += xv.x * w0 + xv.y * w1 + xv.z * w2 + xv.w * w3;
        }
    }
    #pragma unroll
    for (int ss = 0; ss < TS; ++ss) {
        cur[(size_t)(s0 + ss) * H_DIM + h] = acc2[ss];
    }
}

// Stage one chunk (CH x 256 floats = 32 KB) of currents into LDS, async.
// Layout is linear; lane-contiguous in thread order, so the wave-uniform-base
// + lane*16 DMA semantics of global_load_lds match exactly.
__device__ __forceinline__ void stage_chunk(const float* __restrict__ cur,
                                            float* lds_dst, int c, int t) {
    const float* src = cur + (size_t)c * CH * H_DIM;
    #pragma unroll
    for (int i = 0; i < (CH * H_DIM) / (256 * 4); ++i) {   // 8 x 16B per thread
        const float* g = src + (i * 256 + t) * 4;
        float*       l = lds_dst + (i * 256 + t) * 4;
        __builtin_amdgcn_global_load_lds((glob_void*)g, (lds_void*)l, 16, 0, 0);
    }
}

__global__ __launch_bounds__(256)
void snn_scan_out(const float* __restrict__ cur,
                  const float* __restrict__ hw,
                  float*       __restrict__ out) {
    __shared__ __attribute__((aligned(16))) float buf[2][CH * H_DIM];  // 64 KB
    const int t = threadIdx.x;                 // h-chain per thread

    stage_chunk(cur, buf[0], 0, t);

    float mem = 0.f;
    int   sa  = 0;        // first step index at which the neuron is active again
    int   cnt = 0;        // spike count (exact)

    for (int c = 0; c < NCH; ++c) {
        // vmcnt(0)+barrier: drains chunk c's loads, issued one full chunk-scan
        // ago (latency hidden). Chunk c+1 is issued AFTER the drain.
        __syncthreads();
        if (c + 1 < NCH) stage_chunk(cur, buf[(c + 1) & 1], c + 1, t);

        const float* lb = buf[c & 1];
        const int s_base = c * CH;
        #pragma unroll
        for (int j = 0; j < CH; ++j) {
            float ic  = lb[j * H_DIM + t];     // lanes consecutive: 2-way = free
            int   s   = s_base + j;
            // refractory: mem==0 during it; spike at s => inactive s+1,s+2.
            float icg = (sa <= s) ? ic : 0.f;
            float m   = fmaf(0.95f, mem, icg);
            bool  sp  = (m >= 1.0f);
            cnt += sp ? 1 : 0;
            mem  = sp ? 0.f : m;
            sa   = sp ? (s + 3) : sa;
        }
    }

    // Epilogue: out_mean[o] = Σ_h cnt[h] * W_h[h][o] / S, broadcast over batch.
    __syncthreads();
    buf[0][t] = (float)cnt;                    // reuse LDS
    __syncthreads();
    if (t < O_DIM) {
        float a = 0.f;
        #pragma unroll 8
        for (int k = 0; k < H_DIM; ++k) a += buf[0][k] * hw[k * O_DIM + t];
        a *= (1.0f / (float)S_LEN);
        #pragma unroll
        for (int b = 0; b < B_SZ; ++b) out[b * O_DIM + t] = a;
    }
}

extern "C" void kernel_launch(void* const* d_in, const int* in_sizes, int n_in,
                              void* d_out, int out_size, void* d_ws, size_t ws_size,
                              hipStream_t stream) {
    const float4* x4 = (const float4*)d_in[0];       // [32,4096,512] f32
    const float*  iw = (const float*) d_in[1];       // [512,256] f32
    const float*  hw = (const float*) d_in[2];       // [256,128] f32
    float* out = (float*)d_out;                      // [32,128] f32
    float* cur = (float*)d_ws;                       // currents [4096,256] f32 = 4 MB

    hipLaunchKernelGGL(fused_mean_proj, dim3(S_LEN / TS), dim3(256), 0, stream,
                       x4, iw, cur);
    hipLaunchKernelGGL(snn_scan_out, dim3(1), dim3(256), 0, stream,
                       cur, hw, out);
}

// Round 4
// 471.483 us; speedup vs baseline: 1.2590x; 1.1659x over previous
//
#include <hip/hip_runtime.h>
#include <stdint.h>

// SpikingNeuralNetwork: B=32, S=4096, D=512, H=256, OUT=128
// out = broadcast_B( (1/S) * (Σ_s spikes[s,:]) @ W_h ), LIF scan over
// currents = x.mean(0) @ W_in.
//
// Kernel A (fused_mean_proj): fused batch-mean + input projection (reads x
//   once, 268 MB, HBM-bound). Stores currents TRANSPOSED at float4 granularity
//   cur4[s/4][h] so A-stores and B-loads are both coalesced. Block 0 zeroes
//   d_out for B's atomics.
// Kernel B (snn_scan_out): LIF scan, 4 blocks × 64 lanes (1 wave/CU), one
//   neuron chain per lane. Chunks of 64 steps staged via
//   __builtin_amdgcn_global_load_lds (16B) into a double-buffered LDS
//   (2 × 16 KB); single-wave __syncthreads = pure vmcnt drain, issued one full
//   chunk-scan after the loads (latency hidden; R2's 4-wave skew + 32KB queue
//   removed). Chunk copied LDS→regs before the scan; sched_barrier stops the
//   compiler from sinking reads into the dependency chain (R1 failure mode).
//   Fused recurrence: u_s = sp_{s-1} ? 0 : fma(0.95, u_{s-1}, sp_{s-2}?0:ic_s)
//   — bit-exact to the reference; serial cycle = fma→cndmask ≈ 8 cyc/step
//   (cmp runs parallel with fma, both consume u_{s-1}).

#define S_LEN 4096
#define D_DIM 512
#define H_DIM 256
#define O_DIM 128
#define B_SZ  32
#define TS    8                 // s-rows per block in kernel A
#define CH    64                // scan steps per chunk
#define NCH   (S_LEN / CH)      // 64 chunks
#define ROWS  (CH / 4)          // 16 float4 rows per chunk

typedef const __attribute__((address_space(1))) void  glob_void;
typedef       __attribute__((address_space(3))) void  lds_void;

__global__ __launch_bounds__(256)
void fused_mean_proj(const float4* __restrict__ x4,
                     const float*  __restrict__ iw,
                     float4*       __restrict__ cur4,
                     float*        __restrict__ out) {
    __shared__ float4 xm4[TS * D_DIM / 4];     // 8 rows x 512 f32 = 16 KB
    const int t   = threadIdx.x;
    const int s0  = blockIdx.x * TS;
    const int SD4 = S_LEN * D_DIM / 4;
    const size_t base = (size_t)s0 * (D_DIM / 4);

    if (blockIdx.x == 0) {                     // zero out[] for B's atomicAdd
        for (int i = t; i < B_SZ * O_DIM; i += 256) out[i] = 0.f;
    }

    // Stage 1: sum x[b, s0:s0+TS, :] over b (order-preserving, 8 loads in flight).
    float4 acc[4];
    #pragma unroll
    for (int k = 0; k < 4; ++k) acc[k] = make_float4(0.f, 0.f, 0.f, 0.f);

    for (int b = 0; b < B_SZ; b += 2) {
        const float4* p0 = x4 + (size_t)b * SD4 + base;
        const float4* p1 = p0 + SD4;
        float4 v0[4], v1[4];
        #pragma unroll
        for (int k = 0; k < 4; ++k) v0[k] = p0[t + k * 256];
        #pragma unroll
        for (int k = 0; k < 4; ++k) v1[k] = p1[t + k * 256];
        #pragma unroll
        for (int k = 0; k < 4; ++k) {
            acc[k].x += v0[k].x; acc[k].y += v0[k].y; acc[k].z += v0[k].z; acc[k].w += v0[k].w;
            acc[k].x += v1[k].x; acc[k].y += v1[k].y; acc[k].z += v1[k].z; acc[k].w += v1[k].w;
        }
    }
    const float inv = 1.0f / (float)B_SZ;
    #pragma unroll
    for (int k = 0; k < 4; ++k) {
        float4 a = acc[k];
        a.x *= inv; a.y *= inv; a.z *= inv; a.w *= inv;
        xm4[t + k * 256] = a;
    }
    __syncthreads();

    // Stage 2: currents[s0+ss][h] = Σ_d xm[ss][d] * W_in[d][h]; thread = h.
    const int h = t;
    float acc2[TS];
    #pragma unroll
    for (int ss = 0; ss < TS; ++ss) acc2[ss] = 0.f;

    for (int d4 = 0; d4 < D_DIM / 4; ++d4) {
        const int d = d4 * 4;
        float w0 = iw[(d + 0) * H_DIM + h];
        float w1 = iw[(d + 1) * H_DIM + h];
        float w2 = iw[(d + 2) * H_DIM + h];
        float w3 = iw[(d + 3) * H_DIM + h];
        #pragma unroll
        for (int ss = 0; ss < TS; ++ss) {
            float4 xv = xm4[ss * (D_DIM / 4) + d4];   // same-addr broadcast: free
            acc2[ss] += xv.x * w0 + xv.y * w1 + xv.z * w2 + xv.w * w3;
        }
    }
    // Transposed-by-4 store: cur4[(s0/4)+{0,1}][h]; lane h contiguous = coalesced.
    const int g0 = (blockIdx.x * 2) * H_DIM + h;
    cur4[g0]         = make_float4(acc2[0], acc2[1], acc2[2], acc2[3]);
    cur4[g0 + H_DIM] = make_float4(acc2[4], acc2[5], acc2[6], acc2[7]);
}

// One LIF step, fused form (bit-exact to reference):
//   ict = sp2 ? 0 : ic;  t = fma(0.95, u, ict);  u = sp1 ? 0 : t;
//   sp = (u >= 1);  cnt += sp;  shift history.
#define LIF_STEP(IC) {                          \
    float ict = sp2 ? 0.f : (IC);               \
    float tt  = fmaf(0.95f, u, ict);            \
    u   = sp1 ? 0.f : tt;                       \
    bool sp = (u >= 1.0f);                      \
    cnt += sp ? 1 : 0;                          \
    sp2 = sp1; sp1 = sp; }

__global__ __launch_bounds__(64)
void snn_scan_out(const float4* __restrict__ cur4,
                  const float*  __restrict__ hw,
                  float*        __restrict__ out) {
    __shared__ __attribute__((aligned(16))) float4 lbuf[2][ROWS * 64];  // 2 x 16 KB
    __shared__ float cl[64];
    const int lane  = threadIdx.x;             // 0..63, one neuron chain per lane
    const int hbase = blockIdx.x * 64;         // 4 blocks cover h=0..255

    // Stage chunk 0. DMA dst = wave-uniform base + lane*16: layout matches.
    #pragma unroll
    for (int r = 0; r < ROWS; ++r) {
        const float4* g = cur4 + (size_t)r * H_DIM + hbase + lane;
        __builtin_amdgcn_global_load_lds((glob_void*)g,
                                         (lds_void*)&lbuf[0][r * 64 + lane], 16, 0, 0);
    }

    float u = 0.f;                             // memU_{s-1}
    int   cnt = 0;
    bool  sp1 = false, sp2 = false;

    for (int c = 0; c < NCH; ++c) {
        // Drains chunk c's DMA (issued one full chunk-scan ago). 1 wave: no skew.
        __syncthreads();
        if (c + 1 < NCH) {
            #pragma unroll
            for (int r = 0; r < ROWS; ++r) {
                const float4* g = cur4 + (size_t)((c + 1) * ROWS + r) * H_DIM + hbase + lane;
                __builtin_amdgcn_global_load_lds((glob_void*)g,
                                                 (lds_void*)&lbuf[(c + 1) & 1][r * 64 + lane],
                                                 16, 0, 0);
            }
        }
        // Whole chunk LDS -> registers up front (16 x ds_read_b128, pipelined
        // lgkmcnt), then pin the order so reads can't sink into the chain.
        const float4* lb = lbuf[c & 1];
        float4 v[ROWS];
        #pragma unroll
        for (int r = 0; r < ROWS; ++r) v[r] = lb[r * 64 + lane];
        __builtin_amdgcn_sched_barrier(0);

        #pragma unroll
        for (int r = 0; r < ROWS; ++r) {
            LIF_STEP(v[r].x); LIF_STEP(v[r].y); LIF_STEP(v[r].z); LIF_STEP(v[r].w);
        }
    }

    // Epilogue: partial out_mean over this block's 64 neurons, atomic-combined.
    __syncthreads();
    cl[lane] = (float)cnt;
    __syncthreads();
    float a0 = 0.f, a1 = 0.f;
    #pragma unroll 8
    for (int k = 0; k < 64; ++k) {
        float c = cl[k];
        const float* w = hw + (size_t)(hbase + k) * O_DIM;
        a0 = fmaf(c, w[lane], a0);
        a1 = fmaf(c, w[lane + 64], a1);
    }
    a0 *= (1.0f / (float)S_LEN);
    a1 *= (1.0f / (float)S_LEN);
    for (int b = 0; b < B_SZ; ++b) {
        atomicAdd(out + b * O_DIM + lane,      a0);
        atomicAdd(out + b * O_DIM + lane + 64, a1);
    }
}

extern "C" void kernel_launch(void* const* d_in, const int* in_sizes, int n_in,
                              void* d_out, int out_size, void* d_ws, size_t ws_size,
                              hipStream_t stream) {
    const float4* x4 = (const float4*)d_in[0];       // [32,4096,512] f32
    const float*  iw = (const float*) d_in[1];       // [512,256] f32
    const float*  hw = (const float*) d_in[2];       // [256,128] f32
    float* out   = (float*)d_out;                    // [32,128] f32
    float4* cur4 = (float4*)d_ws;                    // [1024][256] float4 = 4 MB

    hipLaunchKernelGGL(fused_mean_proj, dim3(S_LEN / TS), dim3(256), 0, stream,
                       x4, iw, cur4, out);
    hipLaunchKernelGGL(snn_scan_out, dim3(4), dim3(64), 0, stream,
                       cur4, hw, out);
}